// Round 1
// baseline (80529.785 us; speedup 1.0000x reference)
//
#include <hip/hip_runtime.h>
#include <hip/hip_bf16.h>

// Problem constants (fixed by the reference)
constexpr int kB  = 1024;   // batch
constexpr int kT  = 512;    // time steps
constexpr int kF  = 32;     // input features
constexpr int kE  = 16;     // embed dim
constexpr int kXC = 48;     // F + E
constexpr int kH  = 128;    // hidden
constexpr int kG3 = 384;    // 3*H
constexpr int kBB = 4;      // batch rows per block
constexpr int kNB = kB / kBB; // 256 blocks = 1 per CU

__device__ __forceinline__ float sigmf(float v) { return 1.0f / (1.0f + __expf(-v)); }
// tanh via exp; saturates correctly at +/-1 for large |v| (exp -> 0 or inf)
__device__ __forceinline__ float tanhfast(float v) { return 2.0f / (1.0f + __expf(-2.0f * v)) - 1.0f; }

// ---------------------------------------------------------------------------
// K1: layer-0 GRU, persistent weights in VGPRs.
// 384 threads: thread j owns gate-row j of W_ih0 (48 regs) + W_hh0 (128 regs).
// Per step: full dot products in-thread (no reduction), gates via LDS exchange.
// h0 sequence written to workspace for layer 1.
// ---------------------------------------------------------------------------
template <typename ST>
__global__ __launch_bounds__(384, 2) void gru_l0(
    const float* __restrict__ x, const int* __restrict__ tick,
    const float* __restrict__ embed,
    const float* __restrict__ Wih, const float* __restrict__ Whh,
    const float* __restrict__ bih, const float* __restrict__ bhh,
    ST* __restrict__ h0seq)
{
    __shared__ __align__(16) float xc[2][kBB][kXC];  // staged xcat_t (double buffered); [32:48)=emb, constant
    __shared__ __align__(16) float hb[kBB][kH];      // h state
    __shared__ __align__(16) float rb[kBB][kH];      // r gate
    __shared__ __align__(16) float zb[kBB][kH];      // z gate

    const int tid = threadIdx.x;
    const int j   = tid;                 // owned gate row, 0..383
    const int b0  = blockIdx.x * kBB;

    // ---- persistent weights -> registers (fully unrolled => stays in VGPRs)
    float wih[kXC], whh[kH];
    {
        const float4* p = (const float4*)(Wih + (size_t)j * kXC);
#pragma unroll
        for (int k = 0; k < kXC / 4; k++) { float4 v = p[k]; wih[4*k]=v.x; wih[4*k+1]=v.y; wih[4*k+2]=v.z; wih[4*k+3]=v.w; }
        const float4* q = (const float4*)(Whh + (size_t)j * kH);
#pragma unroll
        for (int k = 0; k < kH / 4; k++) { float4 v = q[k]; whh[4*k]=v.x; whh[4*k+1]=v.y; whh[4*k+2]=v.z; whh[4*k+3]=v.w; }
    }
    const float bi = bih[j], bh = bhh[j];

    // ---- init LDS: h=0; embed slots of both xc buffers (constant over t)
    for (int i = tid; i < kBB * kH; i += 384) ((float*)hb)[i] = 0.0f;
    if (tid < kBB * kE) {
        int lb = tid / kE, k = tid % kE;
        float e = embed[(size_t)tick[b0 + lb] * kE + k];
        xc[0][lb][kF + k] = e;
        xc[1][lb][kF + k] = e;
    }
    // loader role: tid<128 stages x (one float each), software-pipelined 1 step ahead
    const int llb = tid >> 5, lk = tid & 31;
    float xreg = 0.0f;
    if (tid < kBB * kF) {
        const size_t base = (size_t)(b0 + llb) * kT * kF + lk;
        xc[0][llb][lk] = x[base];          // t=0
        xreg = x[base + kF];               // t=1 prefetched
    }
    __syncthreads();

    float sv[kBB], tv[kBB];
    for (int t = 0; t < kT; t++) {
        const int cur = t & 1, nxt = cur ^ 1;
        // phase 1: dots. LDS reads are wave-broadcast (all lanes same addr) => conflict-free.
#pragma unroll
        for (int b = 0; b < kBB; b++) {
            float s = bi;
            const float4* xv = (const float4*)xc[cur][b];
#pragma unroll
            for (int k = 0; k < kXC / 4; k++) { float4 v = xv[k]; s += wih[4*k]*v.x + wih[4*k+1]*v.y + wih[4*k+2]*v.z + wih[4*k+3]*v.w; }
            float tt = bh;
            const float4* hv = (const float4*)hb[b];
#pragma unroll
            for (int k = 0; k < kH / 4; k++) { float4 v = hv[k]; tt += whh[4*k]*v.x + whh[4*k+1]*v.y + whh[4*k+2]*v.z + whh[4*k+3]*v.w; }
            sv[b] = s; tv[b] = tt;
        }
        // loader: commit prefetched x_{t+1} to the other buffer, issue load for t+2
        if (tid < kBB * kF) {
            if (t + 1 < kT) xc[nxt][llb][lk] = xreg;
            if (t + 2 < kT) xreg = x[((size_t)(b0 + llb) * kT + (t + 2)) * kF + lk];
        }
        // phase 2: r/z gates -> LDS
        if (j < 2 * kH) {
#pragma unroll
            for (int b = 0; b < kBB; b++) {
                float g = sigmf(sv[b] + tv[b]);
                if (j < kH) rb[b][j] = g; else zb[b][j - kH] = g;
            }
        }
        __syncthreads();
        // phase 3: n gate + state update (thread j>=256 owns hidden unit j-256)
        if (j >= 2 * kH) {
            const int i = j - 2 * kH;
#pragma unroll
            for (int b = 0; b < kBB; b++) {
                float r = rb[b][i], z = zb[b][i];
                float n = tanhfast(sv[b] + r * tv[b]);
                float hn = (1.0f - z) * n + z * hb[b][i];
                hb[b][i] = hn;
                h0seq[((size_t)(b0 + b) * kT + t) * kH + i] = (ST)hn;  // coalesced 512B/batch
            }
        }
        __syncthreads();
    }
}

// ---------------------------------------------------------------------------
// K3: layer-1 GRU + head. 768 threads:
//   group A (tid<384): owns W_ih1 row j  -> gx1[j] from streamed h0_t
//   group B (tid>=384): owns W_hh1 row j -> gh1[j] from h1 state in LDS
// Gates combined via LDS by threads 0..511 (one per (batch, hidden unit)).
// ---------------------------------------------------------------------------
template <typename ST>
__global__ __launch_bounds__(768, 3) void gru_l1_head(
    const ST* __restrict__ h0seq,
    const float* __restrict__ Wih, const float* __restrict__ Whh,
    const float* __restrict__ bih, const float* __restrict__ bhh,
    const float* __restrict__ hw1, const float* __restrict__ hb1,
    const float* __restrict__ hw2, const float* __restrict__ hb2,
    float* __restrict__ out)
{
    __shared__ __align__(16) float h0b[2][kBB][kH];  // staged h0_t (double buffered)
    __shared__ __align__(16) float h1[kBB][kH];      // layer-1 state
    __shared__ __align__(16) float gx[kBB][kG3];     // W_ih1 @ h0_t + b_ih1
    __shared__ __align__(16) float gh[kBB][kG3];     // W_hh1 @ h1  + b_hh1

    const int tid = threadIdx.x;
    const int b0  = blockIdx.x * kBB;
    const bool isA = tid < kG3;
    const int j = isA ? tid : tid - kG3;

    float w[kH];
    {
        const float4* p = (const float4*)((isA ? Wih : Whh) + (size_t)j * kH);
#pragma unroll
        for (int k = 0; k < kH / 4; k++) { float4 v = p[k]; w[4*k]=v.x; w[4*k+1]=v.y; w[4*k+2]=v.z; w[4*k+3]=v.w; }
    }
    const float bias = isA ? bih[j] : bhh[j];

    for (int i = tid; i < kBB * kH; i += 768) ((float*)h1)[i] = 0.0f;
    const int llb = tid >> 7, lk = tid & 127;        // loader/gate role for tid<512
    float hreg = 0.0f;
    if (tid < kBB * kH) {
        h0b[0][llb][lk] = (float)h0seq[(size_t)(b0 + llb) * kT * kH + lk];
        hreg = (float)h0seq[((size_t)(b0 + llb) * kT + 1) * kH + lk];
    }
    __syncthreads();

    for (int t = 0; t < kT; t++) {
        const int cur = t & 1, nxt = cur ^ 1;
        float acc[kBB];
        if (isA) {  // wave-uniform branch (waves 0..5)
#pragma unroll
            for (int b = 0; b < kBB; b++) {
                float a = bias;
                const float4* hv = (const float4*)h0b[cur][b];
#pragma unroll
                for (int k = 0; k < kH / 4; k++) { float4 v = hv[k]; a += w[4*k]*v.x + w[4*k+1]*v.y + w[4*k+2]*v.z + w[4*k+3]*v.w; }
                acc[b] = a;
            }
#pragma unroll
            for (int b = 0; b < kBB; b++) gx[b][j] = acc[b];
        } else {    // waves 6..11
#pragma unroll
            for (int b = 0; b < kBB; b++) {
                float a = bias;
                const float4* hv = (const float4*)h1[b];
#pragma unroll
                for (int k = 0; k < kH / 4; k++) { float4 v = hv[k]; a += w[4*k]*v.x + w[4*k+1]*v.y + w[4*k+2]*v.z + w[4*k+3]*v.w; }
                acc[b] = a;
            }
#pragma unroll
            for (int b = 0; b < kBB; b++) gh[b][j] = acc[b];
        }
        // loader: commit h0_{t+1}, prefetch h0_{t+2}
        if (tid < kBB * kH) {
            if (t + 1 < kT) h0b[nxt][llb][lk] = hreg;
            if (t + 2 < kT) hreg = (float)h0seq[((size_t)(b0 + llb) * kT + (t + 2)) * kH + lk];
        }
        __syncthreads();
        // gate + state update: thread (b,i) for tid<512
        if (tid < kBB * kH) {
            const int b = llb, i = lk;
            float r = sigmf(gx[b][i] + gh[b][i]);
            float z = sigmf(gx[b][kH + i] + gh[b][kH + i]);
            float n = tanhfast(gx[b][2 * kH + i] + r * gh[b][2 * kH + i]);
            h1[b][i] = (1.0f - z) * n + z * h1[b][i];
        }
        __syncthreads();
    }

    // ---- head: hid = relu(h1_last @ W1^T + b1); y = hid @ W2^T + b2
    if (tid < kBB * kH) {
        const int b = llb, i = lk;
        float a = hb1[i];
        const float4* wp = (const float4*)(hw1 + (size_t)i * kH);
        const float4* hv = (const float4*)h1[b];
#pragma unroll
        for (int k = 0; k < kH / 4; k++) { float4 wv = wp[k]; float4 v = hv[k]; a += wv.x*v.x + wv.y*v.y + wv.z*v.z + wv.w*v.w; }
        gx[b][i] = fmaxf(a, 0.0f);   // reuse gx as hid buffer
    }
    __syncthreads();
    if (tid < kBB) {
        float a = hb2[0];
        for (int k = 0; k < kH; k++) a += gx[tid][k] * hw2[k];
        out[b0 + tid] = a;
    }
}

extern "C" void kernel_launch(void* const* d_in, const int* in_sizes, int n_in,
                              void* d_out, int out_size, void* d_ws, size_t ws_size,
                              hipStream_t stream)
{
    const float* x     = (const float*)d_in[0];
    const int*   tick  = (const int*)d_in[1];
    const float* embed = (const float*)d_in[2];
    const float* Wih0  = (const float*)d_in[3];
    const float* Whh0  = (const float*)d_in[4];
    const float* bih0  = (const float*)d_in[5];
    const float* bhh0  = (const float*)d_in[6];
    const float* Wih1  = (const float*)d_in[7];
    const float* Whh1  = (const float*)d_in[8];
    const float* bih1  = (const float*)d_in[9];
    const float* bhh1  = (const float*)d_in[10];
    const float* hw1   = (const float*)d_in[11];
    const float* hb1   = (const float*)d_in[12];
    const float* hw2   = (const float*)d_in[13];
    const float* hb2   = (const float*)d_in[14];
    float* out = (float*)d_out;

    const size_t need_f32 = (size_t)kB * kT * kH * sizeof(float);  // 256 MiB
    if (ws_size >= need_f32) {
        float* h0seq = (float*)d_ws;
        gru_l0<float><<<kNB, 384, 0, stream>>>(x, tick, embed, Wih0, Whh0, bih0, bhh0, h0seq);
        gru_l1_head<float><<<kNB, 768, 0, stream>>>(h0seq, Wih1, Whh1, bih1, bhh1, hw1, hb1, hw2, hb2, out);
    } else {
        // workspace too small for fp32 h0 sequence -> store it as bf16 (128 MiB)
        __hip_bfloat16* h0seq = (__hip_bfloat16*)d_ws;
        gru_l0<__hip_bfloat16><<<kNB, 384, 0, stream>>>(x, tick, embed, Wih0, Whh0, bih0, bhh0, h0seq);
        gru_l1_head<__hip_bfloat16><<<kNB, 768, 0, stream>>>(h0seq, Wih1, Whh1, bih1, bhh1, hw1, hb1, hw2, hb2, out);
    }
}

// Round 2
// 5671.887 us; speedup vs baseline: 14.1981x; 14.1981x over previous
//
#include <hip/hip_runtime.h>
#include <hip/hip_bf16.h>

// Problem constants (fixed by the reference)
constexpr int kB  = 1024;   // batch
constexpr int kT  = 512;    // time steps
constexpr int kF  = 32;     // input features
constexpr int kE  = 16;     // embed dim
constexpr int kXC = 48;     // F + E
constexpr int kH  = 128;    // hidden
constexpr int kG3 = 384;    // 3*H
constexpr int kBB = 4;      // batch rows per block
constexpr int kNB = kB / kBB;   // 256 blocks = 1 per CU
constexpr int kTc = 64;     // chunk length (time steps per pipeline stage)
constexpr int kNC = kT / kTc;   // 8 chunks

__device__ __forceinline__ float sigmf(float v) { return 1.0f / (1.0f + __expf(-v)); }
__device__ __forceinline__ float tanhfast(float v) { return 2.0f / (1.0f + __expf(-2.0f * v)) - 1.0f; }

// Half-row dot: w is a SMALL per-thread register array (<=256B -> promote-alloca
// vectorizes it; the round-1 kernel's 704B arrays went to scratch = 195GB HBM).
// v points at LDS; reads are 2-address-per-wave (free 2-way aliasing).
template <int N4>
__device__ __forceinline__ float dotf4(const float4 (&w)[N4], const float4* __restrict__ v, float init) {
    float4 a = make_float4(0.f, 0.f, 0.f, 0.f);
#pragma unroll
    for (int k = 0; k < N4; k++) {
        float4 x = v[k];
        a.x = fmaf(w[k].x, x.x, a.x);
        a.y = fmaf(w[k].y, x.y, a.y);
        a.z = fmaf(w[k].z, x.z, a.z);
        a.w = fmaf(w[k].w, x.w, a.w);
    }
    return init + ((a.x + a.y) + (a.z + a.w));
}

// ---------------------------------------------------------------------------
// K1: layer-0 GRU for one chunk of kTc steps. 768 threads; lane pair (2r, 2r+1)
// owns row r of [W_ih0 | W_hh0]: thread holds 24 + 64 weight floats (two small
// register arrays). Partial dots combined with __shfl_xor(.,1).
// ---------------------------------------------------------------------------
__global__ __launch_bounds__(768, 3) void gru_l0_chunk(
    const float* __restrict__ x, const int* __restrict__ tick,
    const float* __restrict__ embed,
    const float* __restrict__ Wih, const float* __restrict__ Whh,
    const float* __restrict__ bih, const float* __restrict__ bhh,
    float* __restrict__ h0c, int chunk)
{
    __shared__ __align__(16) float xc[2][kBB][kXC];  // staged xcat_t, double buffered
    __shared__ __align__(16) float hb[kBB][kH];      // h state
    __shared__ __align__(16) float rb[kBB][kH];      // r gate
    __shared__ __align__(16) float zb[kBB][kH];      // z gate

    const int tid = threadIdx.x;
    const int r = tid >> 1, p = tid & 1;             // row, pair-half
    const int b0 = blockIdx.x * kBB;
    const int t0 = chunk * kTc;

    float4 wi[6], wh[16];                            // 96B + 256B register arrays
    {
        const float4* P = (const float4*)(Wih + (size_t)r * kXC + p * 24);
#pragma unroll
        for (int k = 0; k < 6; k++) wi[k] = P[k];
        const float4* Q = (const float4*)(Whh + (size_t)r * kH + p * 64);
#pragma unroll
        for (int k = 0; k < 16; k++) wh[k] = Q[k];
    }
    const float bi = p ? 0.0f : bih[r];
    const float bh = p ? 0.0f : bhh[r];

    // init state: chunk 0 -> zeros; else carry last h of previous chunk
    if (chunk == 0) {
        for (int i = tid; i < kBB * kH; i += 768) ((float*)hb)[i] = 0.0f;
    } else if (tid < kBB * kH) {
        int b = tid >> 7, i = tid & 127;
        hb[b][i] = h0c[((size_t)(b0 + b) * kTc + (kTc - 1)) * kH + i];
    }
    // embed slots (constant over t) in both xc buffers
    if (tid < kBB * kE) {
        int lb = tid >> 4, k = tid & 15;
        float e = embed[(size_t)tick[b0 + lb] * kE + k];
        xc[0][lb][kF + k] = e;
        xc[1][lb][kF + k] = e;
    }
    // x loader role (tid<128), software-pipelined one step ahead
    const int llb = tid >> 5, lk = tid & 31;
    float xreg = 0.0f;
    if (tid < kBB * kF) {
        size_t base = ((size_t)(b0 + llb) * kT + t0) * kF + lk;
        xc[0][llb][lk] = x[base];
        xreg = x[base + kF];
    }
    __syncthreads();

    float sv[kBB], tv[kBB];
    for (int t = 0; t < kTc; t++) {
        const int cur = t & 1, nxt = cur ^ 1;
#pragma unroll
        for (int b = 0; b < kBB; b++) {
            sv[b] = dotf4(wi, (const float4*)&xc[cur][b][0] + p * 6, bi);
            tv[b] = dotf4(wh, (const float4*)&hb[b][0] + p * 16, bh);
        }
#pragma unroll
        for (int b = 0; b < kBB; b++) {
            sv[b] += __shfl_xor(sv[b], 1);
            tv[b] += __shfl_xor(tv[b], 1);
        }
        if (tid < kBB * kF) {
            if (t + 1 < kTc) xc[nxt][llb][lk] = xreg;
            if (t + 2 < kTc) xreg = x[((size_t)(b0 + llb) * kT + (t0 + t + 2)) * kF + lk];
        }
        if (!p && r < 2 * kH) {
#pragma unroll
            for (int b = 0; b < kBB; b++) {
                float g = sigmf(sv[b] + tv[b]);
                if (r < kH) rb[b][r] = g; else zb[b][r - kH] = g;
            }
        }
        __syncthreads();
        if (!p && r >= 2 * kH) {
            const int i = r - 2 * kH;
#pragma unroll
            for (int b = 0; b < kBB; b++) {
                float rr = rb[b][i], zz = zb[b][i];
                float n = tanhfast(sv[b] + rr * tv[b]);
                float hn = (1.0f - zz) * n + zz * hb[b][i];
                hb[b][i] = hn;
                h0c[((size_t)(b0 + b) * kTc + t) * kH + i] = hn;
            }
        }
        __syncthreads();
    }
}

// ---------------------------------------------------------------------------
// K2: gx1_chunk = h0_chunk @ W_ih1^T + b_ih1  (pure GEMM, non-recurrent).
// Pair-split rows (64 floats/thread). Each block: its 4 batches x 64 steps.
// ---------------------------------------------------------------------------
__global__ __launch_bounds__(768, 3) void gx1_gemm(
    const float* __restrict__ h0c,
    const float* __restrict__ Wih, const float* __restrict__ bih,
    float* __restrict__ gx1c)
{
    __shared__ __align__(16) float hrow[8][kH];      // 8 staged h0 rows
    __shared__ __align__(16) float gout[8][kG3];     // 8 output rows

    const int tid = threadIdx.x;
    const int r = tid >> 1, p = tid & 1;
    const int b0 = blockIdx.x * kBB;

    float4 wi[16];
    {
        const float4* P = (const float4*)(Wih + (size_t)r * kH + p * 64);
#pragma unroll
        for (int k = 0; k < 16; k++) wi[k] = P[k];
    }
    const float bi = p ? 0.0f : bih[r];

    for (int b = 0; b < kBB; b++) {
        for (int g = 0; g < kTc / 8; g++) {
            if (tid < 256) {                          // stage 8 rows, coalesced float4
                int u = tid >> 5, k4 = tid & 31;
                ((float4*)&hrow[u][0])[k4] =
                    ((const float4*)(h0c + ((size_t)(b0 + b) * kTc + g * 8 + u) * kH))[k4];
            }
            __syncthreads();
#pragma unroll
            for (int u = 0; u < 8; u++) {
                float s = dotf4(wi, (const float4*)&hrow[u][0] + p * 16, bi);
                s += __shfl_xor(s, 1);
                if (!p) gout[u][r] = s;
            }
            __syncthreads();
            {                                         // store 12KB, coalesced float4
                int u = tid / 96, c4 = tid % 96;
                ((float4*)(gx1c + ((size_t)(b0 + b) * kTc + g * 8 + u) * kG3))[c4] =
                    ((const float4*)&gout[u][0])[c4];
            }
            __syncthreads();
        }
    }
}

// ---------------------------------------------------------------------------
// K3: layer-1 GRU for one chunk, consuming precomputed gx1. Pair-split W_hh1
// (64 floats/thread). gx1 staged to LDS double-buffered, prefetched one step
// ahead. Final chunk also runs the MLP head.
// ---------------------------------------------------------------------------
__global__ __launch_bounds__(768, 3) void gru_l1_chunk(
    const float* __restrict__ gx1c,
    const float* __restrict__ Whh, const float* __restrict__ bhh,
    float* __restrict__ h1s, int chunk,
    const float* __restrict__ hw1, const float* __restrict__ hb1,
    const float* __restrict__ hw2, const float* __restrict__ hb2,
    float* __restrict__ out)
{
    __shared__ __align__(16) float gxb[2][kBB][kG3]; // staged gx1_t (double buffered)
    __shared__ __align__(16) float hb[kBB][kH];      // h1 state
    __shared__ __align__(16) float rb[kBB][kH];
    __shared__ __align__(16) float zb[kBB][kH];

    const int tid = threadIdx.x;
    const int r = tid >> 1, p = tid & 1;
    const int b0 = blockIdx.x * kBB;

    float4 wh[16];
    {
        const float4* Q = (const float4*)(Whh + (size_t)r * kH + p * 64);
#pragma unroll
        for (int k = 0; k < 16; k++) wh[k] = Q[k];
    }
    const float bh = p ? 0.0f : bhh[r];

    if (chunk == 0) {
        for (int i = tid; i < kBB * kH; i += 768) ((float*)hb)[i] = 0.0f;
    } else if (tid < kBB * kH) {
        int b = tid >> 7, i = tid & 127;
        hb[b][i] = h1s[(size_t)(b0 + b) * kH + i];
    }
    // gx loader role: 384 threads, one float4 each (1536B/batch-row, coalesced)
    const int glb = tid / 96, gk = tid % 96;
    float4 greg = make_float4(0.f, 0.f, 0.f, 0.f);
    if (tid < kBB * 96) {
        ((float4*)&gxb[0][glb][0])[gk] =
            ((const float4*)(gx1c + ((size_t)(b0 + glb) * kTc + 0) * kG3))[gk];
        greg = ((const float4*)(gx1c + ((size_t)(b0 + glb) * kTc + 1) * kG3))[gk];
    }
    __syncthreads();

    float tv[kBB];
    for (int t = 0; t < kTc; t++) {
        const int cur = t & 1, nxt = cur ^ 1;
#pragma unroll
        for (int b = 0; b < kBB; b++) tv[b] = dotf4(wh, (const float4*)&hb[b][0] + p * 16, bh);
#pragma unroll
        for (int b = 0; b < kBB; b++) tv[b] += __shfl_xor(tv[b], 1);
        if (tid < kBB * 96) {
            if (t + 1 < kTc) ((float4*)&gxb[nxt][glb][0])[gk] = greg;
            if (t + 2 < kTc) greg = ((const float4*)(gx1c + ((size_t)(b0 + glb) * kTc + t + 2) * kG3))[gk];
        }
        if (!p && r < 2 * kH) {
#pragma unroll
            for (int b = 0; b < kBB; b++) {
                float g = sigmf(gxb[cur][b][r] + tv[b]);
                if (r < kH) rb[b][r] = g; else zb[b][r - kH] = g;
            }
        }
        __syncthreads();
        if (!p && r >= 2 * kH) {
            const int i = r - 2 * kH;
#pragma unroll
            for (int b = 0; b < kBB; b++) {
                float rr = rb[b][i], zz = zb[b][i];
                float n = tanhfast(gxb[cur][b][r] + rr * tv[b]);
                hb[b][i] = (1.0f - zz) * n + zz * hb[b][i];
            }
        }
        __syncthreads();
    }
    // persist h1 state for next chunk
    if (tid < kBB * kH) {
        int b = tid >> 7, i = tid & 127;
        h1s[(size_t)(b0 + b) * kH + i] = hb[b][i];
    }
    // head on the last chunk
    if (chunk == kNC - 1) {
        if (tid < kBB * kH) {
            int b = tid >> 7, i = tid & 127;
            float a = hb1[i];
            const float4* wp = (const float4*)(hw1 + (size_t)i * kH);
            const float4* hv = (const float4*)&hb[b][0];
            float4 ac = make_float4(0.f, 0.f, 0.f, 0.f);
#pragma unroll
            for (int k = 0; k < kH / 4; k++) {
                float4 w = wp[k], v = hv[k];
                ac.x = fmaf(w.x, v.x, ac.x);
                ac.y = fmaf(w.y, v.y, ac.y);
                ac.z = fmaf(w.z, v.z, ac.z);
                ac.w = fmaf(w.w, v.w, ac.w);
            }
            a += (ac.x + ac.y) + (ac.z + ac.w);
            rb[b][i] = fmaxf(a, 0.0f);               // reuse rb as hid buffer
        }
        __syncthreads();
        if (tid < kBB) {
            float a = hb2[0];
            for (int k = 0; k < kH; k++) a += rb[tid][k] * hw2[k];
            out[b0 + tid] = a;
        }
    }
}

extern "C" void kernel_launch(void* const* d_in, const int* in_sizes, int n_in,
                              void* d_out, int out_size, void* d_ws, size_t ws_size,
                              hipStream_t stream)
{
    const float* x     = (const float*)d_in[0];
    const int*   tick  = (const int*)d_in[1];
    const float* embed = (const float*)d_in[2];
    const float* Wih0  = (const float*)d_in[3];
    const float* Whh0  = (const float*)d_in[4];
    const float* bih0  = (const float*)d_in[5];
    const float* bhh0  = (const float*)d_in[6];
    const float* Wih1  = (const float*)d_in[7];
    const float* Whh1  = (const float*)d_in[8];
    const float* bih1  = (const float*)d_in[9];
    const float* bhh1  = (const float*)d_in[10];
    const float* hw1   = (const float*)d_in[11];
    const float* hb1   = (const float*)d_in[12];
    const float* hw2   = (const float*)d_in[13];
    const float* hb2   = (const float*)d_in[14];
    float* out = (float*)d_out;

    // ws layout: h0_chunk 32MB | gx1_chunk 96MB | h1_state 512KB  (~128.5MB total)
    char* wsb = (char*)d_ws;
    float* h0c  = (float*)wsb;
    float* gx1c = (float*)(wsb + (size_t)kB * kTc * kH * sizeof(float));
    float* h1s  = (float*)(wsb + (size_t)kB * kTc * kH * sizeof(float)
                               + (size_t)kB * kTc * kG3 * sizeof(float));

    for (int c = 0; c < kNC; c++) {
        gru_l0_chunk<<<kNB, 768, 0, stream>>>(x, tick, embed, Wih0, Whh0, bih0, bhh0, h0c, c);
        gx1_gemm<<<kNB, 768, 0, stream>>>(h0c, Wih1, bih1, gx1c);
        gru_l1_chunk<<<kNB, 768, 0, stream>>>(gx1c, Whh1, bhh1, h1s, c, hw1, hb1, hw2, hb2, out);
    }
}